// Round 10
// baseline (245.046 us; speedup 1.0000x reference)
//
#include <hip/hip_runtime.h>

// SoftDecisionTree: BATCH=1M, DIM=64, DEPTH=7 -> 127 nodes, 128 leaves.
// Round 10 = round 9 (MFMA logits, W f16 in block LDS XOR-swizzled, f16 P in
// per-wave LDS, line-complete plain stores, zero main-loop barriers, pipelined
// x loads, fmaf-select walk) with ONE lever:
//   P node stride 40 -> 32 B  =>  LDS = 16KB W + 16KB P = 32KB exactly
//   __launch_bounds__(256,5)  =>  5 blocks/CU (160KB LDS), 20 waves/CU (+25%).
// Accepted cost: some 4-way LDS bank conflicts return (P writes and depth-6
// walk reads share banks at stride 32) -- ~1.4-1.6x on a minority of LDS ops,
// small vs the memory-wait-dominated wall. R9 proved wave concurrency is the
// binding limiter (+33% waves -> -8.2% time).

typedef float v4f __attribute__((ext_vector_type(4)));
typedef _Float16 h8 __attribute__((ext_vector_type(8)));
typedef unsigned int u32;
typedef u32 u32x2 __attribute__((ext_vector_type(2)));

constexpr int BATCH = 1 << 20;
constexpr int PSTRIDE = 32;             // bytes per node: 16 rows * 2B, no pad
constexpr int PWAVE = 128 * PSTRIDE;    // 4096 B per wave
constexpr int W_BYTES = 128 * 128;      // 16 KB: 128 nodes x 64 f16
constexpr int P_OFF = W_BYTES;

__device__ __forceinline__ float fast_sigmoid(float z) {
    float e = __builtin_amdgcn_exp2f(z * -1.44269504088896340736f);
    return __builtin_amdgcn_rcpf(1.0f + e);
}

__device__ __forceinline__ u32 pk2(float a, float b) {
    return __builtin_bit_cast(u32, __builtin_amdgcn_cvt_pkrtz(a, b));
}

__device__ __forceinline__ h8 cvt8(v4f lo, v4f hi) {
    union { u32 w[4]; h8 v; } u;
    u.w[0] = pk2(lo.x, lo.y);
    u.w[1] = pk2(lo.z, lo.w);
    u.w[2] = pk2(hi.x, hi.y);
    u.w[3] = pk2(hi.z, hi.w);
    return u.v;
}

__global__ __launch_bounds__(256, 5) void sdt_kernel(
    const float* __restrict__ x,
    const float* __restrict__ w,
    const float* __restrict__ bias,
    const float* __restrict__ leaf,
    float* __restrict__ pred_out,
    float* __restrict__ lp_out)
{
    __shared__ __align__(16) unsigned char smem[W_BYTES + 4 * PWAVE];  // 32 KB

    const int tid  = threadIdx.x;
    const int lane = tid & 63;
    const int wave = tid >> 6;
    const int lc = lane & 15, lq = lane >> 4;   // MFMA fragment coords
    const int j = lane & 7,   rsub = lane >> 3; // walk coords

    unsigned char* WL = smem;                    // block-shared weights (f16, swizzled)
    unsigned char* Pw = smem + P_OFF + wave * PWAVE;

    // ---- one-time: stage W -> LDS f16 with XOR swizzle; node 127 zeroed ----
    for (int idx = tid; idx < 128 * 8; idx += 256) {
        int node = idx >> 3, c = idx & 7;        // c = 16B chunk within the 128B row
        v4f f0 = {}, f1 = {};
        if (node < 127) {
            const float* sp = w + node * 64 + c * 8;
            f0 = *(const v4f*)sp; f1 = *(const v4f*)(sp + 4);
        }
        int off = node * 128 + ((c * 16) ^ ((node & 7) << 4));
        *(h8*)(WL + off) = cvt8(f0, f1);
    }

    float bias_v[8];
#pragma unroll
    for (int ct = 0; ct < 8; ++ct) {
        int node = ct * 16 + lc; if (node > 126) node = 126;
        bias_v[ct] = bias[node];
    }
    v4f leafv[4];
#pragma unroll
    for (int s = 0; s < 4; ++s) leafv[s] = *(const v4f*)(leaf + 32 * s + 4 * j);

    // per-lane select constants: (b ? p : 1-p) == fmaf(s, p, o)
    const int b2 = (j >> 2) & 1, b3 = (j >> 1) & 1, b4 = j & 1;
    const float s2 = b2 ? 1.f : -1.f, o2 = b2 ? 0.f : 1.f;
    const float s3 = b3 ? 1.f : -1.f, o3 = b3 ? 0.f : 1.f;
    const float s4 = b4 ? 1.f : -1.f, o4 = b4 ? 0.f : 1.f;

    const int wave_row0 = blockIdx.x * 256 + wave * 16;   // chunk ck adds ck*64
    const int wsw = (lc & 7) << 4;                        // W read swizzle (node&7 == lc&7)

    // ---- prologue: issue chunk-0 x loads ----
    const float* xr0 = x + (size_t)(wave_row0 + lc) * 64 + lq * 8;
    v4f xa = *(const v4f*)xr0,        xb = *(const v4f*)(xr0 + 4);
    v4f xc = *(const v4f*)(xr0 + 32), xd = *(const v4f*)(xr0 + 36);

    __syncthreads();   // W staged (once; main loop has no barriers)

#pragma unroll
    for (int ck = 0; ck < 4; ++ck) {
        const int row0 = wave_row0 + ck * 64;

        // consume raw x regs, immediately re-issue loads for chunk ck+1
        h8 a0 = cvt8(xa, xb);
        h8 a1 = cvt8(xc, xd);
        if (ck < 3) {
            const float* xr = xr0 + (ck + 1) * 64 * 64;
            xa = *(const v4f*)xr;        xb = *(const v4f*)(xr + 4);
            xc = *(const v4f*)(xr + 32); xd = *(const v4f*)(xr + 36);
        }

        // ---- MFMA: 16 rows x 128 node-cols; sigmoid; p -> LDS f16 ----
#pragma unroll
        for (int ct = 0; ct < 8; ++ct) {
            const unsigned char* wrow = WL + (ct * 16 + lc) * 128;
            h8 b0 = *(const h8*)(wrow + ((lq * 16)      ^ wsw));   // K 0..31
            h8 b1 = *(const h8*)(wrow + ((64 + lq * 16) ^ wsw));   // K 32..63
            v4f acc = {};
            acc = __builtin_amdgcn_mfma_f32_16x16x32_f16(a0, b0, acc, 0, 0, 0);
            acc = __builtin_amdgcn_mfma_f32_16x16x32_f16(a1, b1, acc, 0, 0, 0);
            // C layout: col = lane&15, row = (lane>>4)*4 + i
            float s0 = fast_sigmoid(acc[0] + bias_v[ct]);
            float s1 = fast_sigmoid(acc[1] + bias_v[ct]);
            float sS2 = fast_sigmoid(acc[2] + bias_v[ct]);
            float sS3 = fast_sigmoid(acc[3] + bias_v[ct]);
            *(u32x2*)(Pw + (ct * 16 + lc) * PSTRIDE + lq * 8) =
                u32x2{pk2(s0, s1), pk2(sS2, sS3)};               // ds_write_b64
        }

        asm volatile("s_waitcnt lgkmcnt(0)" ::: "memory");  // P visible (same-wave)

        // ---- walk: thread = (row octet rsub, leaf quad j) ----
        auto rd = [&](int node, int row) -> float {
            return (float)*(const _Float16*)(Pw + node * PSTRIDE + row * 2);
        };

        float pa = 0.f, pb = 0.f;
#pragma unroll
        for (int i1 = 0; i1 < 2; ++i1) {
            const int row = rsub + 8 * i1;
            float p0  = rd(0, row);
            float p1a = rd(1, row), p1b = rd(2, row);
            float f01_0 = (1.f - p0) * (1.f - p1a);
            float f01_1 = (1.f - p0) * p1a;
            float f01_2 = p0 * (1.f - p1b);
            float f01_3 = p0 * p1b;
            float acc = 0.f;
            v4f* dst = (v4f*)lp_out + (size_t)(row0 + row) * 32 + j;
#pragma unroll
            for (int seg = 0; seg < 4; ++seg) {
                float f01 = seg == 0 ? f01_0 : seg == 1 ? f01_1 : seg == 2 ? f01_2 : f01_3;
                float P3 = f01 * fmaf(s2, rd(3 + seg, row), o2);
                float P4 = P3  * fmaf(s3, rd(7 + 2 * seg + (j >> 2), row), o3);
                float P5 = P4  * fmaf(s4, rd(15 + 4 * seg + (j >> 1), row), o4);
                const int q = 8 * seg + j;
                float pd5 = rd(31 + q, row);
                float A = P5 * (1.f - pd5), B = P5 * pd5;
                float pl = rd(63 + 2 * q, row), pr = rd(64 + 2 * q, row);
                v4f o = { A * (1.f - pl), A * pl, B * (1.f - pr), B * pr };
                dst[seg * 8] = o;   // lanes j=0..7 tile 8 complete 128B lines
                acc = fmaf(o.x, leafv[seg].x, acc);
                acc = fmaf(o.y, leafv[seg].y, acc);
                acc = fmaf(o.z, leafv[seg].z, acc);
                acc = fmaf(o.w, leafv[seg].w, acc);
            }
            if (i1 == 0) pa = acc; else pb = acc;
        }

        // pred: reduce over the 8 j-lanes of each row
#pragma unroll
        for (int s = 1; s <= 4; s <<= 1) {
            pa += __shfl_xor(pa, s, 64);
            pb += __shfl_xor(pb, s, 64);
        }
        if (j == 0) {
            pred_out[row0 + rsub]     = pa;
            pred_out[row0 + rsub + 8] = pb;
        }
    }
}

extern "C" void kernel_launch(void* const* d_in, const int* in_sizes, int n_in,
                              void* d_out, int out_size, void* d_ws, size_t ws_size,
                              hipStream_t stream) {
    const float* x    = (const float*)d_in[0];
    const float* w    = (const float*)d_in[1];
    const float* bias = (const float*)d_in[2];
    const float* leaf = (const float*)d_in[3];

    float* pred = (float*)d_out;             // BATCH floats
    float* lp   = (float*)d_out + BATCH;     // BATCH x 128 floats

    sdt_kernel<<<BATCH / 256, 256, 0, stream>>>(x, w, bias, leaf, pred, lp);
}

// Round 11
// 167.358 us; speedup vs baseline: 1.4642x; 1.4642x over previous
//
#include <hip/hip_runtime.h>

// SoftDecisionTree: BATCH=1M, DIM=64, DEPTH=7 -> 127 nodes, 128 leaves.
// Round 11 = round 9 EXACTLY (MFMA logits, W f16 in block LDS XOR-swizzled,
// f16 P in per-wave LDS stride-40 (conflict-free; R10 proved stride 32 is an
// 8-way conflict on the walk's hottest reads), line-complete plain stores,
// zero main-loop barriers, pipelined x loads, fmaf-select walk, 4 blocks/CU)
// with ONE lever:
//   persistent-style blocks: grid 4096 -> 1024 (4/CU), 16 chunks per block.
//   - W staged once per 1024 rows instead of once per 256 (-75% stagings,
//     -75% of the syncthreads that re-lockstep the 4 waves)
//   - x-prefetch chain stays warm 16 chunks deep (no cold prologue per 256)
//   - waves drift into phase-staggered steady state -> smoother store issue.

typedef float v4f __attribute__((ext_vector_type(4)));
typedef _Float16 h8 __attribute__((ext_vector_type(8)));
typedef unsigned int u32;
typedef u32 u32x2 __attribute__((ext_vector_type(2)));

constexpr int BATCH = 1 << 20;
constexpr int CHUNKS = 16;              // 64 rows each -> 1024 rows per block
constexpr int GRID = BATCH / (CHUNKS * 64);   // 1024 blocks = 4 per CU
constexpr int PSTRIDE = 40;             // bytes per node: 16 rows * 2B + 8 pad
constexpr int PWAVE = 128 * PSTRIDE;    // 5120 B per wave
constexpr int W_BYTES = 128 * 128;      // 16 KB: 128 nodes x 64 f16
constexpr int P_OFF = W_BYTES;

__device__ __forceinline__ float fast_sigmoid(float z) {
    float e = __builtin_amdgcn_exp2f(z * -1.44269504088896340736f);
    return __builtin_amdgcn_rcpf(1.0f + e);
}

__device__ __forceinline__ u32 pk2(float a, float b) {
    return __builtin_bit_cast(u32, __builtin_amdgcn_cvt_pkrtz(a, b));
}

__device__ __forceinline__ h8 cvt8(v4f lo, v4f hi) {
    union { u32 w[4]; h8 v; } u;
    u.w[0] = pk2(lo.x, lo.y);
    u.w[1] = pk2(lo.z, lo.w);
    u.w[2] = pk2(hi.x, hi.y);
    u.w[3] = pk2(hi.z, hi.w);
    return u.v;
}

__global__ __launch_bounds__(256, 4) void sdt_kernel(
    const float* __restrict__ x,
    const float* __restrict__ w,
    const float* __restrict__ bias,
    const float* __restrict__ leaf,
    float* __restrict__ pred_out,
    float* __restrict__ lp_out)
{
    __shared__ __align__(16) unsigned char smem[W_BYTES + 4 * PWAVE];  // 36.9 KB

    const int tid  = threadIdx.x;
    const int lane = tid & 63;
    const int wave = tid >> 6;
    const int lc = lane & 15, lq = lane >> 4;   // MFMA fragment coords
    const int j = lane & 7,   rsub = lane >> 3; // walk coords

    unsigned char* WL = smem;                    // block-shared weights (f16, swizzled)
    unsigned char* Pw = smem + P_OFF + wave * PWAVE;

    // ---- one-time: stage W -> LDS f16 with XOR swizzle; node 127 zeroed ----
    for (int idx = tid; idx < 128 * 8; idx += 256) {
        int node = idx >> 3, c = idx & 7;        // c = 16B chunk within the 128B row
        v4f f0 = {}, f1 = {};
        if (node < 127) {
            const float* sp = w + node * 64 + c * 8;
            f0 = *(const v4f*)sp; f1 = *(const v4f*)(sp + 4);
        }
        int off = node * 128 + ((c * 16) ^ ((node & 7) << 4));
        *(h8*)(WL + off) = cvt8(f0, f1);
    }

    float bias_v[8];
#pragma unroll
    for (int ct = 0; ct < 8; ++ct) {
        int node = ct * 16 + lc; if (node > 126) node = 126;
        bias_v[ct] = bias[node];
    }
    v4f leafv[4];
#pragma unroll
    for (int s = 0; s < 4; ++s) leafv[s] = *(const v4f*)(leaf + 32 * s + 4 * j);

    // per-lane select constants: (b ? p : 1-p) == fmaf(s, p, o)
    const int b2 = (j >> 2) & 1, b3 = (j >> 1) & 1, b4 = j & 1;
    const float s2 = b2 ? 1.f : -1.f, o2 = b2 ? 0.f : 1.f;
    const float s3 = b3 ? 1.f : -1.f, o3 = b3 ? 0.f : 1.f;
    const float s4 = b4 ? 1.f : -1.f, o4 = b4 ? 0.f : 1.f;

    const int wave_row0 = blockIdx.x * (CHUNKS * 64) + wave * 16;  // + ck*64
    const int wsw = (lc & 7) << 4;                // W read swizzle (node&7 == lc&7)

    // ---- prologue: issue chunk-0 x loads ----
    const float* xr0 = x + (size_t)(wave_row0 + lc) * 64 + lq * 8;
    v4f xa = *(const v4f*)xr0,        xb = *(const v4f*)(xr0 + 4);
    v4f xc = *(const v4f*)(xr0 + 32), xd = *(const v4f*)(xr0 + 36);

    __syncthreads();   // W staged (once; main loop has no barriers)

    for (int ck = 0; ck < CHUNKS; ++ck) {
        const int row0 = wave_row0 + ck * 64;

        // consume raw x regs, immediately re-issue loads for chunk ck+1
        h8 a0 = cvt8(xa, xb);
        h8 a1 = cvt8(xc, xd);
        if (ck < CHUNKS - 1) {
            const float* xr = xr0 + (size_t)(ck + 1) * 64 * 64;
            xa = *(const v4f*)xr;        xb = *(const v4f*)(xr + 4);
            xc = *(const v4f*)(xr + 32); xd = *(const v4f*)(xr + 36);
        }

        // ---- MFMA: 16 rows x 128 node-cols; sigmoid; p -> LDS f16 ----
#pragma unroll
        for (int ct = 0; ct < 8; ++ct) {
            const unsigned char* wrow = WL + (ct * 16 + lc) * 128;
            h8 b0 = *(const h8*)(wrow + ((lq * 16)      ^ wsw));   // K 0..31
            h8 b1 = *(const h8*)(wrow + ((64 + lq * 16) ^ wsw));   // K 32..63
            v4f acc = {};
            acc = __builtin_amdgcn_mfma_f32_16x16x32_f16(a0, b0, acc, 0, 0, 0);
            acc = __builtin_amdgcn_mfma_f32_16x16x32_f16(a1, b1, acc, 0, 0, 0);
            // C layout: col = lane&15, row = (lane>>4)*4 + i
            float s0 = fast_sigmoid(acc[0] + bias_v[ct]);
            float s1 = fast_sigmoid(acc[1] + bias_v[ct]);
            float sS2 = fast_sigmoid(acc[2] + bias_v[ct]);
            float sS3 = fast_sigmoid(acc[3] + bias_v[ct]);
            *(u32x2*)(Pw + (ct * 16 + lc) * PSTRIDE + lq * 8) =
                u32x2{pk2(s0, s1), pk2(sS2, sS3)};               // ds_write_b64
        }

        asm volatile("s_waitcnt lgkmcnt(0)" ::: "memory");  // P visible (same-wave)

        // ---- walk: thread = (row octet rsub, leaf quad j) ----
        auto rd = [&](int node, int row) -> float {
            return (float)*(const _Float16*)(Pw + node * PSTRIDE + row * 2);
        };

        float pa = 0.f, pb = 0.f;
#pragma unroll
        for (int i1 = 0; i1 < 2; ++i1) {
            const int row = rsub + 8 * i1;
            float p0  = rd(0, row);
            float p1a = rd(1, row), p1b = rd(2, row);
            float f01_0 = (1.f - p0) * (1.f - p1a);
            float f01_1 = (1.f - p0) * p1a;
            float f01_2 = p0 * (1.f - p1b);
            float f01_3 = p0 * p1b;
            float acc = 0.f;
            v4f* dst = (v4f*)lp_out + (size_t)(row0 + row) * 32 + j;
#pragma unroll
            for (int seg = 0; seg < 4; ++seg) {
                float f01 = seg == 0 ? f01_0 : seg == 1 ? f01_1 : seg == 2 ? f01_2 : f01_3;
                float P3 = f01 * fmaf(s2, rd(3 + seg, row), o2);
                float P4 = P3  * fmaf(s3, rd(7 + 2 * seg + (j >> 2), row), o3);
                float P5 = P4  * fmaf(s4, rd(15 + 4 * seg + (j >> 1), row), o4);
                const int q = 8 * seg + j;
                float pd5 = rd(31 + q, row);
                float A = P5 * (1.f - pd5), B = P5 * pd5;
                float pl = rd(63 + 2 * q, row), pr = rd(64 + 2 * q, row);
                v4f o = { A * (1.f - pl), A * pl, B * (1.f - pr), B * pr };
                dst[seg * 8] = o;   // lanes j=0..7 tile 8 complete 128B lines
                acc = fmaf(o.x, leafv[seg].x, acc);
                acc = fmaf(o.y, leafv[seg].y, acc);
                acc = fmaf(o.z, leafv[seg].z, acc);
                acc = fmaf(o.w, leafv[seg].w, acc);
            }
            if (i1 == 0) pa = acc; else pb = acc;
        }

        // pred: reduce over the 8 j-lanes of each row
#pragma unroll
        for (int s = 1; s <= 4; s <<= 1) {
            pa += __shfl_xor(pa, s, 64);
            pb += __shfl_xor(pb, s, 64);
        }
        if (j == 0) {
            pred_out[row0 + rsub]     = pa;
            pred_out[row0 + rsub + 8] = pb;
        }
    }
}

extern "C" void kernel_launch(void* const* d_in, const int* in_sizes, int n_in,
                              void* d_out, int out_size, void* d_ws, size_t ws_size,
                              hipStream_t stream) {
    const float* x    = (const float*)d_in[0];
    const float* w    = (const float*)d_in[1];
    const float* bias = (const float*)d_in[2];
    const float* leaf = (const float*)d_in[3];

    float* pred = (float*)d_out;             // BATCH floats
    float* lp   = (float*)d_out + BATCH;     // BATCH x 128 floats

    sdt_kernel<<<GRID, 256, 0, stream>>>(x, w, bias, leaf, pred, lp);
}

// Round 12
// 163.976 us; speedup vs baseline: 1.4944x; 1.0206x over previous
//
#include <hip/hip_runtime.h>

// SoftDecisionTree: BATCH=1M, DIM=64, DEPTH=7 -> 127 nodes, 128 leaves.
// Round 12 = exact revert to round 9, the best measured configuration
// (164.0 us). Final form:
//   - logits via mfma_f32_16x16x32_f16; W staged once to block LDS (f16,
//     XOR-swizzled), B-frags ds_read_b128 per chunk -> VGPR stays ~96,
//     4 blocks/CU / 16 waves/CU (the occupancy win, R9: -8.2%).
//   - p = sigmoid f16 in per-wave LDS, node stride 40B (conflict-free;
//     stride 32 is an 8-way conflict on the walk's hot reads -- R10: -50%).
//   - walk: lane=(row-octet, leaf-quad); each store instruction's 64 lanes
//     tile 8 COMPLETE 128B lines (the write-amplification fix, R2/R4: 4.5x
//     WRITE_SIZE -> ideal). Plain stores (NT hint: null, R8).
//   - x loads software-pipelined one chunk ahead (R6: -3%).
//   - zero main-loop barriers; pred via shfl_xor reduce.
// Ledger of refuted levers: NT stores (R8 null), 5 blocks/CU (R10, LDS/bank
// structural), persistent blocks (R11 null), W-reload from global (R7, serial
// L2 chain -50%). Remaining gap to copy-roofline (~148-164 us vs 125 pure) is
// the mixed read/write-stream limit.

typedef float v4f __attribute__((ext_vector_type(4)));
typedef _Float16 h8 __attribute__((ext_vector_type(8)));
typedef unsigned int u32;
typedef u32 u32x2 __attribute__((ext_vector_type(2)));

constexpr int BATCH = 1 << 20;
constexpr int PSTRIDE = 40;             // bytes per node: 16 rows * 2B + 8 pad
constexpr int PWAVE = 128 * PSTRIDE;    // 5120 B per wave
constexpr int W_BYTES = 128 * 128;      // 16 KB: 128 nodes x 64 f16
constexpr int P_OFF = W_BYTES;

__device__ __forceinline__ float fast_sigmoid(float z) {
    float e = __builtin_amdgcn_exp2f(z * -1.44269504088896340736f);
    return __builtin_amdgcn_rcpf(1.0f + e);
}

__device__ __forceinline__ u32 pk2(float a, float b) {
    return __builtin_bit_cast(u32, __builtin_amdgcn_cvt_pkrtz(a, b));
}

__device__ __forceinline__ h8 cvt8(v4f lo, v4f hi) {
    union { u32 w[4]; h8 v; } u;
    u.w[0] = pk2(lo.x, lo.y);
    u.w[1] = pk2(lo.z, lo.w);
    u.w[2] = pk2(hi.x, hi.y);
    u.w[3] = pk2(hi.z, hi.w);
    return u.v;
}

__global__ __launch_bounds__(256, 4) void sdt_kernel(
    const float* __restrict__ x,
    const float* __restrict__ w,
    const float* __restrict__ bias,
    const float* __restrict__ leaf,
    float* __restrict__ pred_out,
    float* __restrict__ lp_out)
{
    __shared__ __align__(16) unsigned char smem[W_BYTES + 4 * PWAVE];  // 36.9 KB

    const int tid  = threadIdx.x;
    const int lane = tid & 63;
    const int wave = tid >> 6;
    const int lc = lane & 15, lq = lane >> 4;   // MFMA fragment coords
    const int j = lane & 7,   rsub = lane >> 3; // walk coords

    unsigned char* WL = smem;                    // block-shared weights (f16, swizzled)
    unsigned char* Pw = smem + P_OFF + wave * PWAVE;

    // ---- one-time: stage W -> LDS f16 with XOR swizzle; node 127 zeroed ----
    for (int idx = tid; idx < 128 * 8; idx += 256) {
        int node = idx >> 3, c = idx & 7;        // c = 16B chunk within the 128B row
        v4f f0 = {}, f1 = {};
        if (node < 127) {
            const float* sp = w + node * 64 + c * 8;
            f0 = *(const v4f*)sp; f1 = *(const v4f*)(sp + 4);
        }
        int off = node * 128 + ((c * 16) ^ ((node & 7) << 4));
        *(h8*)(WL + off) = cvt8(f0, f1);
    }

    float bias_v[8];
#pragma unroll
    for (int ct = 0; ct < 8; ++ct) {
        int node = ct * 16 + lc; if (node > 126) node = 126;
        bias_v[ct] = bias[node];
    }
    v4f leafv[4];
#pragma unroll
    for (int s = 0; s < 4; ++s) leafv[s] = *(const v4f*)(leaf + 32 * s + 4 * j);

    // per-lane select constants: (b ? p : 1-p) == fmaf(s, p, o)
    const int b2 = (j >> 2) & 1, b3 = (j >> 1) & 1, b4 = j & 1;
    const float s2 = b2 ? 1.f : -1.f, o2 = b2 ? 0.f : 1.f;
    const float s3 = b3 ? 1.f : -1.f, o3 = b3 ? 0.f : 1.f;
    const float s4 = b4 ? 1.f : -1.f, o4 = b4 ? 0.f : 1.f;

    const int wave_row0 = blockIdx.x * 256 + wave * 16;   // chunk ck adds ck*64
    const int wsw = (lc & 7) << 4;                        // W read swizzle (node&7 == lc&7)

    // ---- prologue: issue chunk-0 x loads ----
    const float* xr0 = x + (size_t)(wave_row0 + lc) * 64 + lq * 8;
    v4f xa = *(const v4f*)xr0,        xb = *(const v4f*)(xr0 + 4);
    v4f xc = *(const v4f*)(xr0 + 32), xd = *(const v4f*)(xr0 + 36);

    __syncthreads();   // W staged (once; main loop has no barriers)

#pragma unroll
    for (int ck = 0; ck < 4; ++ck) {
        const int row0 = wave_row0 + ck * 64;

        // consume raw x regs, immediately re-issue loads for chunk ck+1
        h8 a0 = cvt8(xa, xb);
        h8 a1 = cvt8(xc, xd);
        if (ck < 3) {
            const float* xr = xr0 + (ck + 1) * 64 * 64;
            xa = *(const v4f*)xr;        xb = *(const v4f*)(xr + 4);
            xc = *(const v4f*)(xr + 32); xd = *(const v4f*)(xr + 36);
        }

        // ---- MFMA: 16 rows x 128 node-cols; sigmoid; p -> LDS f16 ----
#pragma unroll
        for (int ct = 0; ct < 8; ++ct) {
            const unsigned char* wrow = WL + (ct * 16 + lc) * 128;
            h8 b0 = *(const h8*)(wrow + ((lq * 16)      ^ wsw));   // K 0..31
            h8 b1 = *(const h8*)(wrow + ((64 + lq * 16) ^ wsw));   // K 32..63
            v4f acc = {};
            acc = __builtin_amdgcn_mfma_f32_16x16x32_f16(a0, b0, acc, 0, 0, 0);
            acc = __builtin_amdgcn_mfma_f32_16x16x32_f16(a1, b1, acc, 0, 0, 0);
            // C layout: col = lane&15, row = (lane>>4)*4 + i
            float s0 = fast_sigmoid(acc[0] + bias_v[ct]);
            float s1 = fast_sigmoid(acc[1] + bias_v[ct]);
            float sS2 = fast_sigmoid(acc[2] + bias_v[ct]);
            float sS3 = fast_sigmoid(acc[3] + bias_v[ct]);
            *(u32x2*)(Pw + (ct * 16 + lc) * PSTRIDE + lq * 8) =
                u32x2{pk2(s0, s1), pk2(sS2, sS3)};               // ds_write_b64
        }

        asm volatile("s_waitcnt lgkmcnt(0)" ::: "memory");  // P visible (same-wave)

        // ---- walk: thread = (row octet rsub, leaf quad j) ----
        auto rd = [&](int node, int row) -> float {
            return (float)*(const _Float16*)(Pw + node * PSTRIDE + row * 2);
        };

        float pa = 0.f, pb = 0.f;
#pragma unroll
        for (int i1 = 0; i1 < 2; ++i1) {
            const int row = rsub + 8 * i1;
            float p0  = rd(0, row);
            float p1a = rd(1, row), p1b = rd(2, row);
            float f01_0 = (1.f - p0) * (1.f - p1a);
            float f01_1 = (1.f - p0) * p1a;
            float f01_2 = p0 * (1.f - p1b);
            float f01_3 = p0 * p1b;
            float acc = 0.f;
            v4f* dst = (v4f*)lp_out + (size_t)(row0 + row) * 32 + j;
#pragma unroll
            for (int seg = 0; seg < 4; ++seg) {
                float f01 = seg == 0 ? f01_0 : seg == 1 ? f01_1 : seg == 2 ? f01_2 : f01_3;
                float P3 = f01 * fmaf(s2, rd(3 + seg, row), o2);
                float P4 = P3  * fmaf(s3, rd(7 + 2 * seg + (j >> 2), row), o3);
                float P5 = P4  * fmaf(s4, rd(15 + 4 * seg + (j >> 1), row), o4);
                const int q = 8 * seg + j;
                float pd5 = rd(31 + q, row);
                float A = P5 * (1.f - pd5), B = P5 * pd5;
                float pl = rd(63 + 2 * q, row), pr = rd(64 + 2 * q, row);
                v4f o = { A * (1.f - pl), A * pl, B * (1.f - pr), B * pr };
                dst[seg * 8] = o;   // lanes j=0..7 tile 8 complete 128B lines
                acc = fmaf(o.x, leafv[seg].x, acc);
                acc = fmaf(o.y, leafv[seg].y, acc);
                acc = fmaf(o.z, leafv[seg].z, acc);
                acc = fmaf(o.w, leafv[seg].w, acc);
            }
            if (i1 == 0) pa = acc; else pb = acc;
        }

        // pred: reduce over the 8 j-lanes of each row
#pragma unroll
        for (int s = 1; s <= 4; s <<= 1) {
            pa += __shfl_xor(pa, s, 64);
            pb += __shfl_xor(pb, s, 64);
        }
        if (j == 0) {
            pred_out[row0 + rsub]     = pa;
            pred_out[row0 + rsub + 8] = pb;
        }
    }
}

extern "C" void kernel_launch(void* const* d_in, const int* in_sizes, int n_in,
                              void* d_out, int out_size, void* d_ws, size_t ws_size,
                              hipStream_t stream) {
    const float* x    = (const float*)d_in[0];
    const float* w    = (const float*)d_in[1];
    const float* bias = (const float*)d_in[2];
    const float* leaf = (const float*)d_in[3];

    float* pred = (float*)d_out;             // BATCH floats
    float* lp   = (float*)d_out + BATCH;     // BATCH x 128 floats

    sdt_kernel<<<BATCH / 256, 256, 0, stream>>>(x, w, bias, leaf, pred, lp);
}